// Round 1
// baseline (2079.951 us; speedup 1.0000x reference)
//
#include <hip/hip_runtime.h>

#define M_ROWS 16384
#define DIM    512
#define NCODES 8192

// ws layout (bytes)
#define WS_X    0         // 16384 f32  row |x|^2, numpy-pairwise bitwise
#define WS_KEY  65536     // 16384 u64  packed (dist_bits<<32)|idx
#define WS_IDX  196608    // 16384 i32
#define WS_PART 262144    // 2048 f64   per-block loss partials
#define NPART   2048

// ---------------- K0: init keys ----------------
__global__ void k0_init(unsigned long long* __restrict__ key) {
    int i = blockIdx.x * blockDim.x + threadIdx.x;
    if (i < M_ROWS) key[i] = ~0ull;
}

// ---------------- K1: X = np.sum(x*x, axis=1), bitwise numpy pairwise ----------------
// numpy pairwise: 512 -> S(256)+S(256); 256 -> S(128)+S(128);
// 128-block: r[0..7]=a[0..7]; 15x r[j]+=a[i+j]; ((r0+r1)+(r2+r3))+((r4+r5)+(r6+r7))
__global__ void k1_rowsum(const float* __restrict__ x, float* __restrict__ X) {
    int row = blockIdx.x * blockDim.x + threadIdx.x;
    if (row >= M_ROWS) return;
    const float* a = x + (size_t)row * DIM;
    float b[4];
#pragma unroll
    for (int blk = 0; blk < 4; ++blk) {
        const float* p = a + blk * 128;
        float r[8];
#pragma unroll
        for (int j = 0; j < 8; ++j) r[j] = __fmul_rn(p[j], p[j]);
        for (int i = 8; i < 128; i += 8) {
#pragma unroll
            for (int j = 0; j < 8; ++j)
                r[j] = __fadd_rn(r[j], __fmul_rn(p[i + j], p[i + j]));
        }
        b[blk] = __fadd_rn(__fadd_rn(__fadd_rn(r[0], r[1]), __fadd_rn(r[2], r[3])),
                           __fadd_rn(__fadd_rn(r[4], r[5]), __fadd_rn(r[6], r[7])));
    }
    X[row] = __fadd_rn(__fadd_rn(b[0], b[1]), __fadd_rn(b[2], b[3]));
}

// ---------------- K2: fused distance GEMM + argmin ----------------
#define BM 128   // rows per block
#define BK 64    // codes per tile
#define BD 64    // depth per tile
#define KY 4     // code-range splits (occupancy)
#define CODES_PER_Y (NCODES / KY)   // 2048

__global__ __launch_bounds__(512) void k2_argmin(
    const float* __restrict__ x, const float* __restrict__ E,
    const float* __restrict__ Xs, unsigned long long* __restrict__ key)
{
    __shared__ float xs[BD][BM + 4];   // [d][row]  33792 B
    __shared__ float es[BD][BK + 4];   // [d][code] 17408 B

    const int tid = threadIdx.x;
    const int tx = tid & 15;           // code group
    const int ty = tid >> 4;           // row group [0,32)
    const int row0 = blockIdx.x * BM;
    const int cbase = blockIdx.y * CODES_PER_Y;

    float Xr[4];
#pragma unroll
    for (int i = 0; i < 4; ++i) Xr[i] = Xs[row0 + ty * 4 + i];

    float bestD[4];
    int   bestI[4];
#pragma unroll
    for (int i = 0; i < 4; ++i) { bestD[i] = __builtin_inff(); bestI[i] = 0x7fffffff; }

    for (int ct = 0; ct < CODES_PER_Y / BK; ++ct) {
        const int c0 = cbase + ct * BK;
        float acc[4][4];
#pragma unroll
        for (int i = 0; i < 4; ++i)
#pragma unroll
            for (int j = 0; j < 4; ++j) acc[i][j] = 0.f;

        for (int dt = 0; dt < DIM / BD; ++dt) {
            const int d0 = dt * BD;
            __syncthreads();
            {
                const int d4 = tid & 15;       // float4 column
                const int r  = tid >> 4;       // [0,32)
#pragma unroll
                for (int k = 0; k < 4; ++k) {  // 128 rows of x
                    int rr = r + 32 * k;
                    float4 v = *(const float4*)(x + (size_t)(row0 + rr) * DIM + d0 + d4 * 4);
                    xs[d4 * 4 + 0][rr] = v.x; xs[d4 * 4 + 1][rr] = v.y;
                    xs[d4 * 4 + 2][rr] = v.z; xs[d4 * 4 + 3][rr] = v.w;
                }
#pragma unroll
                for (int k = 0; k < 2; ++k) {  // 64 codes of E
                    int cc = r + 32 * k;
                    float4 v = *(const float4*)(E + (size_t)(c0 + cc) * DIM + d0 + d4 * 4);
                    es[d4 * 4 + 0][cc] = v.x; es[d4 * 4 + 1][cc] = v.y;
                    es[d4 * 4 + 2][cc] = v.z; es[d4 * 4 + 3][cc] = v.w;
                }
            }
            __syncthreads();
#pragma unroll 8
            for (int d = 0; d < BD; ++d) {
                float4 xv = *(const float4*)&xs[d][ty * 4];
                float4 ev = *(const float4*)&es[d][tx * 4];
                float xa[4] = {xv.x, xv.y, xv.z, xv.w};
                float ea[4] = {ev.x, ev.y, ev.z, ev.w};
#pragma unroll
                for (int i = 0; i < 4; ++i)
#pragma unroll
                    for (int j = 0; j < 4; ++j)
                        acc[i][j] = __fmaf_rn(xa[i], ea[j], acc[i][j]);
            }
        }
        // epilogue: dist = fl(X - fl(2*dot)); strict < keeps lowest index (codes ascend per thread)
#pragma unroll
        for (int j = 0; j < 4; ++j) {
            int code = c0 + tx * 4 + j;
#pragma unroll
            for (int i = 0; i < 4; ++i) {
                float dist = __fsub_rn(Xr[i], __fmul_rn(2.0f, acc[i][j]));
                if (dist < bestD[i]) { bestD[i] = dist; bestI[i] = code; }
            }
        }
    }

    // merge across the 16 tx-threads of each row (reuse xs/es LDS)
    __syncthreads();
    float* mbd = (float*)&xs[0][0];   // [BM][17]
    int*   mbi = (int*)&es[0][0];     // [BM][17]
#pragma unroll
    for (int i = 0; i < 4; ++i) {
        mbd[(ty * 4 + i) * 17 + tx] = bestD[i];
        mbi[(ty * 4 + i) * 17 + tx] = bestI[i];
    }
    __syncthreads();
    if (tid < BM) {
        float d = mbd[tid * 17 + 0];
        int   idx = mbi[tid * 17 + 0];
#pragma unroll
        for (int t = 1; t < 16; ++t) {
            float d2 = mbd[tid * 17 + t];
            int   i2 = mbi[tid * 17 + t];
            if (d2 < d || (d2 == d && i2 < idx)) { d = d2; idx = i2; }
        }
        // dist > 0 always (X ~ 512 >> |2 x.e|), so float bits are order-preserving
        unsigned long long k = ((unsigned long long)__float_as_uint(d) << 32) | (unsigned)idx;
        atomicMin(&key[row0 + tid], k);
    }
}

// ---------------- K2b: unpack indices ----------------
__global__ void k2b_idx(const unsigned long long* __restrict__ key,
                        int* __restrict__ idxI, float* __restrict__ idxF) {
    int row = blockIdx.x * blockDim.x + threadIdx.x;
    if (row >= M_ROWS) return;
    int idx = (int)(key[row] & 0xffffffffull);
    idxI[row] = idx;
    idxF[row] = (float)idx;
}

// ---------------- K3: gather outputs + loss partials ----------------
__global__ __launch_bounds__(256) void k3_out(
    const float* __restrict__ x, const float* __restrict__ E,
    const int* __restrict__ idxI, float* __restrict__ out0,
    float* __restrict__ out1, double* __restrict__ part)
{
    const int n4 = M_ROWS * (DIM / 4);  // 2,097,152 float4 elements
    double loc = 0.0;
    for (int i4 = blockIdx.x * blockDim.x + threadIdx.x; i4 < n4;
         i4 += gridDim.x * blockDim.x) {
        int row = i4 >> 7;
        int d4  = i4 & 127;
        int idx = idxI[row];
        float4 xv = *(const float4*)(x + (size_t)i4 * 4);
        float4 qv = *(const float4*)(E + (size_t)idx * DIM + d4 * 4);
        float4 o0;
        float dx0 = __fsub_rn(qv.x, xv.x);
        float dx1 = __fsub_rn(qv.y, xv.y);
        float dx2 = __fsub_rn(qv.z, xv.z);
        float dx3 = __fsub_rn(qv.w, xv.w);
        o0.x = __fadd_rn(xv.x, dx0);
        o0.y = __fadd_rn(xv.y, dx1);
        o0.z = __fadd_rn(xv.z, dx2);
        o0.w = __fadd_rn(xv.w, dx3);
        *(float4*)(out0 + (size_t)i4 * 4) = o0;
        *(float4*)(out1 + (size_t)i4 * 4) = qv;
        loc += (double)__fmul_rn(dx0, dx0) + (double)__fmul_rn(dx1, dx1)
             + (double)__fmul_rn(dx2, dx2) + (double)__fmul_rn(dx3, dx3);
    }
    // deterministic block reduction
#pragma unroll
    for (int off = 32; off > 0; off >>= 1) loc += __shfl_down(loc, off);
    __shared__ double wsum[4];
    int lane = threadIdx.x & 63, wid = threadIdx.x >> 6;
    if (lane == 0) wsum[wid] = loc;
    __syncthreads();
    if (threadIdx.x == 0)
        part[blockIdx.x] = (wsum[0] + wsum[1]) + (wsum[2] + wsum[3]);
}

// ---------------- K4: finalize losses ----------------
__global__ void k4_final(const double* __restrict__ part, float* __restrict__ outL) {
    __shared__ double s[256];
    double loc = 0.0;
    for (int i = threadIdx.x; i < NPART; i += 256) loc += part[i];
    s[threadIdx.x] = loc;
    __syncthreads();
    for (int st = 128; st > 0; st >>= 1) {
        if (threadIdx.x < st) s[threadIdx.x] += s[threadIdx.x + st];
        __syncthreads();
    }
    if (threadIdx.x == 0) {
        float m = (float)(s[0] / 8388608.0);
        outL[0] = m;   // q_loss
        outL[1] = m;   // e_loss (numerically identical)
    }
}

extern "C" void kernel_launch(void* const* d_in, const int* in_sizes, int n_in,
                              void* d_out, int out_size, void* d_ws, size_t ws_size,
                              hipStream_t stream) {
    const float* x = (const float*)d_in[0];   // [16,1024,512]
    const float* E = (const float*)d_in[1];   // [8192,512]
    float* out = (float*)d_out;
    char* ws = (char*)d_ws;

    float* X                  = (float*)(ws + WS_X);
    unsigned long long* key   = (unsigned long long*)(ws + WS_KEY);
    int* idxI                 = (int*)(ws + WS_IDX);
    double* part              = (double*)(ws + WS_PART);

    float* out0   = out;               // quantized_ste [16,1024,512]
    float* out1   = out + 8388608;     // quantized     [16,1024,512]
    float* outL   = out + 16777216;    // q_loss, e_loss
    float* outIdx = out + 16777218;    // indices [16,1024] as f32

    hipLaunchKernelGGL(k0_init,   dim3(64),      dim3(256), 0, stream, key);
    hipLaunchKernelGGL(k1_rowsum, dim3(64),      dim3(256), 0, stream, x, X);
    hipLaunchKernelGGL(k2_argmin, dim3(128, 4),  dim3(512), 0, stream, x, E, X, key);
    hipLaunchKernelGGL(k2b_idx,   dim3(64),      dim3(256), 0, stream, key, idxI, outIdx);
    hipLaunchKernelGGL(k3_out,    dim3(2048),    dim3(256), 0, stream, x, E, idxI, out0, out1, part);
    hipLaunchKernelGGL(k4_final,  dim3(1),       dim3(256), 0, stream, part, outL);
}